// Round 3
// baseline (106.230 us; speedup 1.0000x reference)
//
#include <hip/hip_runtime.h>

// GPUTimeMask: x (B=64, C=16, T=60000) fp32; starts/widths (NUM_MASKS=2, B) int32.
// Zero x[b, :, t] for t in [start, start+clip(width,1,150)) for each of 2 masks.
//
// Fused streaming kernel, one block per half-row (b, c, half):
//  - no div/mod in the hot loop (t = i*4 within the row)
//  - mask params are wave-uniform scalar loads
//  - uniform early-out: half-rows untouched by any mask span run a pure
//    unrolled float4 copy (>99% of blocks)

#define B_DIM 64
#define C_DIM 16
#define T_DIM 60000
#define MAXW 150

#define T4 (T_DIM / 4)          // 15000 float4 per row
#define HALF4 (T4 / 2)          // 7500 float4 per half-row
#define HALF_T (T_DIM / 2)      // 30000 t-positions per half-row
#define FULL_ITERS (HALF4 / 256)            // 29
#define TAIL (HALF4 - FULL_ITERS * 256)     // 76

__global__ __launch_bounds__(256) void GPUTimeMask_38010460570421_kernel(
    const float4* __restrict__ x,
    const int* __restrict__ starts,   // (2, B) flat
    const int* __restrict__ widths,   // (2, B) flat
    float4* __restrict__ out) {
    int bid = blockIdx.x;             // 0 .. 2047
    int b    = bid >> 5;              // 64 batches
    int ch   = bid & 31;
    int c    = ch >> 1;               // 16 channels
    int half = ch & 1;                // 2 halves per row

    int base4 = (b * C_DIM + c) * T4 + half * HALF4;
    int t0    = half * HALF_T;

    // Wave-uniform (address depends only on blockIdx) -> scalarized loads.
    int s0 = starts[b];
    int s1 = starts[B_DIM + b];
    int w0 = widths[b];
    int w1 = widths[B_DIM + b];
    w0 = min(max(w0, 1), MAXW);
    w1 = min(max(w1, 1), MAXW);
    // Shift spans into half-row-local coordinates.
    int e0 = s0 + w0 - t0;
    int e1 = s1 + w1 - t0;
    s0 -= t0;
    s1 -= t0;

    const float4* __restrict__ src = x + base4;
    float4* __restrict__ dst = out + base4;
    int tid = threadIdx.x;

    bool touched = (e0 > 0 && s0 < HALF_T) || (e1 > 0 && s1 < HALF_T);
    if (!touched) {
        // Pure copy path (uniform branch; >99% of blocks).
        int i = tid;
        #pragma unroll 4
        for (int it = 0; it < FULL_ITERS; ++it, i += 256) {
            dst[i] = src[i];
        }
        if (tid < TAIL) {
            int j = FULL_ITERS * 256 + tid;
            dst[j] = src[j];
        }
    } else {
        int i = tid;
        #pragma unroll 4
        for (int it = 0; it < FULL_ITERS; ++it, i += 256) {
            float4 v = src[i];
            int t = i * 4;
            v.x = ((t   >= s0 && t   < e0) || (t   >= s1 && t   < e1)) ? 0.0f : v.x;
            v.y = ((t+1 >= s0 && t+1 < e0) || (t+1 >= s1 && t+1 < e1)) ? 0.0f : v.y;
            v.z = ((t+2 >= s0 && t+2 < e0) || (t+2 >= s1 && t+2 < e1)) ? 0.0f : v.z;
            v.w = ((t+3 >= s0 && t+3 < e0) || (t+3 >= s1 && t+3 < e1)) ? 0.0f : v.w;
            dst[i] = v;
        }
        if (tid < TAIL) {
            int j = FULL_ITERS * 256 + tid;
            float4 v = src[j];
            int t = j * 4;
            v.x = ((t   >= s0 && t   < e0) || (t   >= s1 && t   < e1)) ? 0.0f : v.x;
            v.y = ((t+1 >= s0 && t+1 < e0) || (t+1 >= s1 && t+1 < e1)) ? 0.0f : v.y;
            v.z = ((t+2 >= s0 && t+2 < e0) || (t+2 >= s1 && t+2 < e1)) ? 0.0f : v.z;
            v.w = ((t+3 >= s0 && t+3 < e0) || (t+3 >= s1 && t+3 < e1)) ? 0.0f : v.w;
            dst[j] = v;
        }
    }
}

extern "C" void kernel_launch(void* const* d_in, const int* in_sizes, int n_in,
                              void* d_out, int out_size, void* d_ws, size_t ws_size,
                              hipStream_t stream) {
    const float4* x = (const float4*)d_in[0];
    const int* starts = (const int*)d_in[1];
    const int* widths = (const int*)d_in[2];
    float4* out = (float4*)d_out;

    // 2048 blocks = 64 batches * 16 channels * 2 half-rows
    hipLaunchKernelGGL(GPUTimeMask_38010460570421_kernel,
                       dim3(B_DIM * C_DIM * 2), dim3(256), 0, stream,
                       x, starts, widths, out);
}

// Round 4
// 88.776 us; speedup vs baseline: 1.1966x; 1.1966x over previous
//
#include <hip/hip_runtime.h>

// GPUTimeMask: x (B=64, C=16, T=60000) fp32; starts/widths (NUM_MASKS=2, B) int32.
// Zero x[b, :, t] for t in [start, start+clip(width,1,150)) for each of 2 masks.
//
// Strategy: pure tuned copy kernel (no-tail mapping, nontemporal float4
// load/store, 15-deep unroll) + tiny fixup kernel zeroing the masked spans
// (<=0.5% of elements). Copy stream has zero reuse -> nt keeps it out of
// L2/LLC.

#define B_DIM 64
#define C_DIM 16
#define T_DIM 60000
#define MAXW 150
#define NUM_MASKS 2

#define TOTAL4 (B_DIM * C_DIM * (T_DIM / 4))   // 15,360,000 float4
#define NBLK 4000
#define NTHR 256
#define K_ITER (TOTAL4 / (NBLK * NTHR))        // 15, exact: 4000*256*15 = 15,360,000

typedef __attribute__((ext_vector_type(4))) float f32x4;

__global__ __launch_bounds__(NTHR) void GPUTimeMask_38010460570421_copy(
    const f32x4* __restrict__ src,
    f32x4* __restrict__ dst) {
    int base = blockIdx.x * (NTHR * K_ITER) + threadIdx.x;
    const f32x4* __restrict__ s = src + base;
    f32x4* __restrict__ d = dst + base;
    f32x4 v[K_ITER];
    #pragma unroll
    for (int k = 0; k < K_ITER; ++k) {
        v[k] = __builtin_nontemporal_load(&s[k * NTHR]);
    }
    #pragma unroll
    for (int k = 0; k < K_ITER; ++k) {
        __builtin_nontemporal_store(v[k], &d[k * NTHR]);
    }
}

__global__ __launch_bounds__(256) void GPUTimeMask_38010460570421_fixup(
    const int* __restrict__ starts,   // (2, B) flat
    const int* __restrict__ widths,   // (2, B) flat
    float* __restrict__ out) {
    int mb = blockIdx.x;              // m*B_DIM + b
    int b  = mb & (B_DIM - 1);

    int s = starts[mb];
    int w = widths[mb];
    w = min(max(w, 1), MAXW);

    int tid = threadIdx.x;
    if (tid < w) {
        long base = (long)b * C_DIM * T_DIM + s + tid;
        #pragma unroll
        for (int c = 0; c < C_DIM; ++c) {
            out[base + (long)c * T_DIM] = 0.0f;
        }
    }
}

extern "C" void kernel_launch(void* const* d_in, const int* in_sizes, int n_in,
                              void* d_out, int out_size, void* d_ws, size_t ws_size,
                              hipStream_t stream) {
    const f32x4* x = (const f32x4*)d_in[0];
    const int* starts = (const int*)d_in[1];
    const int* widths = (const int*)d_in[2];

    hipLaunchKernelGGL(GPUTimeMask_38010460570421_copy,
                       dim3(NBLK), dim3(NTHR), 0, stream,
                       x, (f32x4*)d_out);

    hipLaunchKernelGGL(GPUTimeMask_38010460570421_fixup,
                       dim3(NUM_MASKS * B_DIM), dim3(256), 0, stream,
                       starts, widths, (float*)d_out);
}

// Round 5
// 87.320 us; speedup vs baseline: 1.2166x; 1.0167x over previous
//
#include <hip/hip_runtime.h>

// GPUTimeMask: x (B=64, C=16, T=60000) fp32; starts/widths (NUM_MASKS=2, B) int32.
// Zero x[b, :, t] for t in [start, start+clip(width,1,150)) for each of 2 masks.
//
// Single fused kernel: exact-mapping nontemporal float4 copy (4000 blk x 256
// thr x 15 float4, no tail), then per-block in-place zeroing of any mask-span
// overlap with the block's own range. A block's 3840-float4 range spans at
// most 2 rows; overlap check is uniform and ~98% of blocks skip it.
// __syncthreads() between copy and fixup orders same-address re-stores
// (it drains vmcnt).

#define B_DIM 64
#define C_DIM 16
#define T_DIM 60000
#define MAXW 150
#define NUM_MASKS 2

#define ROW4 (T_DIM / 4)                        // 15000 float4 per row
#define TOTAL4 (B_DIM * C_DIM * ROW4)           // 15,360,000 float4
#define NBLK 4000
#define NTHR 256
#define K_ITER (TOTAL4 / (NBLK * NTHR))         // 15, exact
#define BLK4 (NTHR * K_ITER)                    // 3840 float4 per block

typedef __attribute__((ext_vector_type(4))) float f32x4;

__global__ __launch_bounds__(NTHR) void GPUTimeMask_38010460570421_fused(
    const f32x4* __restrict__ src,
    f32x4* __restrict__ dst,
    const int* __restrict__ starts,   // (2, B) flat
    const int* __restrict__ widths) { // (2, B) flat
    int tid = threadIdx.x;
    int f0 = blockIdx.x * BLK4;       // block's first float4 (flat)
    int f1 = f0 + BLK4;               // exclusive

    // ---- hot copy loop: 15 nt loads batched, then 15 nt stores ----
    const f32x4* __restrict__ s = src + f0 + tid;
    f32x4* __restrict__ d = dst + f0 + tid;
    f32x4 v[K_ITER];
    #pragma unroll
    for (int k = 0; k < K_ITER; ++k) {
        v[k] = __builtin_nontemporal_load(&s[k * NTHR]);
    }
    #pragma unroll
    for (int k = 0; k < K_ITER; ++k) {
        __builtin_nontemporal_store(v[k], &d[k * NTHR]);
    }

    // ---- fixup: zero mask-span overlap within this block's range ----
    // Block range spans at most 2 rows (BLK4 < ROW4).
    int r0 = f0 / ROW4;               // const divisor -> magic mul
    int r1 = (f1 - 1) / ROW4;

    bool need = false;
    #pragma unroll 2
    for (int r = r0; r <= r1; ++r) {
        int b = r >> 4;               // r = b*16 + c
        int lo = max(f0, r * ROW4) * 4 - r * T_DIM;       // row-local float lo
        int hi = min(f1, (r + 1) * ROW4) * 4 - r * T_DIM; // row-local float hi
        #pragma unroll
        for (int m = 0; m < NUM_MASKS; ++m) {
            int sp = starts[m * B_DIM + b];
            int w  = widths[m * B_DIM + b];
            w = min(max(w, 1), MAXW);
            need |= (max(sp, lo) < min(sp + w, hi));
        }
    }
    if (!need) return;

    __syncthreads();                  // drain copy stores before re-storing

    float* outf = (float*)dst;
    #pragma unroll 2
    for (int r = r0; r <= r1; ++r) {
        int b = r >> 4;
        int lo = max(f0, r * ROW4) * 4 - r * T_DIM;
        int hi = min(f1, (r + 1) * ROW4) * 4 - r * T_DIM;
        long rowbase = (long)r * T_DIM;
        #pragma unroll
        for (int m = 0; m < NUM_MASKS; ++m) {
            int sp = starts[m * B_DIM + b];
            int w  = widths[m * B_DIM + b];
            w = min(max(w, 1), MAXW);
            int a = max(sp, lo);
            int e = min(sp + w, hi);
            for (int t = a + tid; t < e; t += NTHR) {
                outf[rowbase + t] = 0.0f;
            }
        }
    }
}

extern "C" void kernel_launch(void* const* d_in, const int* in_sizes, int n_in,
                              void* d_out, int out_size, void* d_ws, size_t ws_size,
                              hipStream_t stream) {
    const f32x4* x = (const f32x4*)d_in[0];
    const int* starts = (const int*)d_in[1];
    const int* widths = (const int*)d_in[2];

    hipLaunchKernelGGL(GPUTimeMask_38010460570421_fused,
                       dim3(NBLK), dim3(NTHR), 0, stream,
                       x, (f32x4*)d_out, starts, widths);
}